// Round 9
// baseline (118.133 us; speedup 1.0000x reference)
//
#include <hip/hip_runtime.h>

// LateralEI: out = GAIN * rownorm(K) @ h, K = 0.8*exp(-d2/0.72) - exp(-d2/2.88)
// z: [8192][2] f32, h: [8192][128] f32, out: [8192][128] f32
//
// R9: discriminating experiment vs the 43us invariant (R4/R6/R7/R8).
// Single-WAVE blocks (64 thr): no barriers, no inter-wave coupling at all.
//  - B double-buffered in REGISTERS across iterations (unroll 2 renames the
//    rotate): MFMA(it) joins on loads issued one full iteration earlier;
//    B(it+1) in flight through the whole body. Loop vmem = only these 8 loads.
//  - z slice (512 k) staged to wave-private LDS by 4 global_load_lds in the
//    preamble (one explicit vmcnt(0) — DMA->ds_read deps are NOT compiler-
//    tracked), read in-loop as quad-uniform ds_read_b128 broadcasts.
//  - grid 4096 = 256 row-tiles x 16 k-slices; ~155 regs -> 3 waves/SIMD,
//    12 independent waves/CU.
// If this is neutral too, the limiter is per-CU TA/L1 on the 512MB B-stream
// (next: LDS-share B across waves). w-math / layouts R2-R8-verified.

typedef float f32x4 __attribute__((ext_vector_type(4)));
typedef short s16x8 __attribute__((ext_vector_type(8)));
typedef unsigned int u32x4 __attribute__((ext_vector_type(4)));

#define NPTS 8192
#define DH 128
#define A_I (-0.5009357781f)  // -log2(e)/(2*1.2^2); A_E = 4*A_I
#define GAIN_C 0.05f

#define NKS 16      // cross-block K-slices (512 k each)
#define KSL 512
#define NITER 16    // 512 / 32
#define NRT 256     // row-tiles (32 rows = 1 wave each)

// ---------- pre-pass: h [8192][128] f32 -> hTf fragment-major bf16 (R4-verified) ----------
// Fragment (k5=k>>5, cf): 512 halfwords at hTf[(k5*8+cf)*512]; chunk for lane
// (q=lane>>4, nf=lane&15) at +lane*8 holds h[k5*32+q*8+j][cf*16+nf], j=0..7.
__global__ __launch_bounds__(256) void h_to_hTf(
    const float* __restrict__ h, unsigned short* __restrict__ hTf) {
  __shared__ unsigned int tileW[DH * 17];  // [n][kp], kp = k-pair 0..15
  const int t = threadIdx.x;
  const int k5 = blockIdx.x;
  const int n = t & 127;
  const int g = t >> 7;  // 0..1
#pragma unroll
  for (int p = 0; p < 8; ++p) {
    const int kp = g * 8 + p;
    unsigned int a = __float_as_uint(h[(k5 * 32 + 2 * kp) * DH + n]);
    unsigned int b = __float_as_uint(h[(k5 * 32 + 2 * kp + 1) * DH + n]);
    a = (a + 0x7fffu + ((a >> 16) & 1u)) >> 16;          // RNE low half
    b = (b + 0x7fffu + ((b >> 16) & 1u)) & 0xffff0000u;  // RNE high half
    tileW[n * 17 + kp] = a | b;
  }
  __syncthreads();
#pragma unroll
  for (int it = 0; it < 2; ++it) {
    const int u = t + it * 256;
    const int cf = u >> 6;
    const int lane = u & 63;
    const int nf = lane & 15;
    const int q = lane >> 4;
    const int n2 = cf * 16 + nf;
    u32x4 val;
#pragma unroll
    for (int i = 0; i < 4; ++i) val[i] = tileW[n2 * 17 + q * 4 + i];
    *(u32x4*)(hTf + k5 * 4096 + u * 8) = val;
  }
}

// ---------- main fused kernel: independent single-wave blocks ----------
__global__ __launch_bounds__(64, 3) void lateral_ei_main(
    const float* __restrict__ z, const unsigned short* __restrict__ hTf,
    unsigned short* __restrict__ partb, float* __restrict__ prs) {
  __shared__ __align__(16) float zxy[KSL * 2];  // 4 KB, wave-private

  const int lane = threadIdx.x;  // 0..63
  const int rt = blockIdx.x & (NRT - 1);
  const int ks = blockIdx.x >> 8;  // 0..NKS-1
  const int i0 = rt * 32;
  const int nf = lane & 15;
  const int q = lane >> 4;
  const int k0 = ks * KSL;

  // zi constants for rows i0+nf, i0+16+nf
  const float zx0 = z[(i0 + nf) * 2], zy0 = z[(i0 + nf) * 2 + 1];
  const float zx1 = z[(i0 + 16 + nf) * 2], zy1 = z[(i0 + 16 + nf) * 2 + 1];
  const float cA0 = A_I * (zx0 * zx0 + zy0 * zy0);
  const float cA1 = A_I * (zx1 * zx1 + zy1 * zy1);
  const float cX0 = -2.f * A_I * zx0, cY0 = -2.f * A_I * zy0;
  const float cX1 = -2.f * A_I * zx1, cY1 = -2.f * A_I * zy1;

  // stage this slice's z (4 KB) into LDS via DMA: 4 x (64 lanes x 16B)
  {
    const char* zs = (const char*)(z + (size_t)k0 * 2);
    char* zd = (char*)zxy;
#pragma unroll
    for (int c = 0; c < 4; ++c)
      __builtin_amdgcn_global_load_lds(
          (const __attribute__((address_space(1))) unsigned int*)(zs + c * 1024 + lane * 16),
          (__attribute__((address_space(3))) unsigned int*)(zd + c * 1024 + lane * 16),
          16, 0, 0);
  }

  // B fragment base; preload iter 0 into the register buffer
  const unsigned short* hb = hTf + (size_t)(ks * 16) * 4096 + lane * 8;
  s16x8 bc[8];
#pragma unroll
  for (int cf = 0; cf < 8; ++cf) bc[cf] = *(const s16x8*)(hb + cf * 512);

  // DMA->ds_read dependency is not compiler-tracked: drain once, before loop.
  asm volatile("s_waitcnt vmcnt(0)" ::: "memory");

  f32x4 acc0[8], acc1[8];
#pragma unroll
  for (int cf = 0; cf < 8; ++cf) {
    acc0[cf] = (f32x4){0.f, 0.f, 0.f, 0.f};
    acc1[cf] = (f32x4){0.f, 0.f, 0.f, 0.f};
  }
  float rs0a = 0.f, rs0b = 0.f, rs1a = 0.f, rs1b = 0.f;

#pragma unroll 2
  for (int it = 0; it < NITER; ++it) {
    // ---- issue B(it+1) first: in flight across this whole body.
    // it=15 reads 8KB past the slice (ks=15: start of partb) — mapped, unused.
    s16x8 bn[8];
#pragma unroll
    for (int cf = 0; cf < 8; ++cf)
      bn[cf] = *(const s16x8*)(hb + (it + 1) * 4096 + cf * 512);

    // ---- z for iter it: quad-uniform LDS broadcast reads (ds_read_b128)
    const float* zp_ = zxy + it * 64 + q * 16;
    const f32x4 zcA = *(const f32x4*)(zp_ + 0);
    const f32x4 zcB = *(const f32x4*)(zp_ + 4);
    const f32x4 zcC = *(const f32x4*)(zp_ + 8);
    const f32x4 zcD = *(const f32x4*)(zp_ + 12);

    // ---- 16 w's (inline m2; verified math path)
    float wv0[8], wv1[8];
#pragma unroll
    for (int j = 0; j < 8; ++j) {
      const f32x4 zp = (j < 2) ? zcA : (j < 4) ? zcB : (j < 6) ? zcC : zcD;
      const float xj = zp[(j & 1) * 2], yj = zp[(j & 1) * 2 + 1];
      const float m2 = fmaf(yj, yj, xj * xj);
      const float u0 = fmaf(cX0, xj, fmaf(cY0, yj, fmaf(A_I, m2, cA0)));
      const float u1 = fmaf(cX1, xj, fmaf(cY1, yj, fmaf(A_I, m2, cA1)));
      const float ei0 = __builtin_amdgcn_exp2f(u0);
      const float ei1 = __builtin_amdgcn_exp2f(u1);
      const float s0 = ei0 * ei0, s1 = ei1 * ei1;
      const float w0 = fmaf(0.8f, s0 * s0, -ei0);  // e_E = e_I^4
      const float w1 = fmaf(0.8f, s1 * s1, -ei1);
      wv0[j] = w0; wv1[j] = w1;
      if (j & 1) { rs0b += w0; rs1b += w1; } else { rs0a += w0; rs1a += w1; }
    }
    union { unsigned int u[4]; s16x8 v; } af0, af1;
#pragma unroll
    for (int p = 0; p < 4; ++p) {
      af0.u[p] = __builtin_amdgcn_perm(__float_as_uint(wv0[2 * p + 1]),
                                       __float_as_uint(wv0[2 * p]), 0x07060302);
      af1.u[p] = __builtin_amdgcn_perm(__float_as_uint(wv1[2 * p + 1]),
                                       __float_as_uint(wv1[2 * p]), 0x07060302);
    }
    const s16x8 a0 = af0.v, a1 = af1.v;

    // ---- 16 MFMAs on bc (loaded one full iteration ago; bn stays in flight)
#pragma unroll
    for (int cf = 0; cf < 8; ++cf) {
      acc0[cf] = __builtin_amdgcn_mfma_f32_16x16x32_bf16(a0, bc[cf], acc0[cf], 0, 0, 0);
      acc1[cf] = __builtin_amdgcn_mfma_f32_16x16x32_bf16(a1, bc[cf], acc1[cf], 0, 0, 0);
    }
    // rotate (unroll-2 register renaming removes the copies)
#pragma unroll
    for (int cf = 0; cf < 8; ++cf) bc[cf] = bn[cf];
  }

  // ---- rowsum: sum 4 quad-partials per row (lanes nf,nf+16,nf+32,nf+48)
  float rs0 = rs0a + rs0b, rs1 = rs1a + rs1b;
  rs0 += __shfl_xor(rs0, 16);
  rs0 += __shfl_xor(rs0, 32);
  rs1 += __shfl_xor(rs1, 16);
  rs1 += __shfl_xor(rs1, 32);
  if (lane < 16) {
    prs[ks * NPTS + i0 + nf] = rs0;
    prs[ks * NPTS + i0 + 16 + nf] = rs1;
  }

  // ---- partial store, bf16 RNE (C/D layout: col=cf*16+nf, row=q*4+r)
  unsigned short* pb = partb + (size_t)ks * (NPTS * DH);
#pragma unroll
  for (int cf = 0; cf < 8; ++cf)
#pragma unroll
    for (int r = 0; r < 4; ++r) {
      unsigned int u0 = __float_as_uint(acc0[cf][r]);
      unsigned int u1 = __float_as_uint(acc1[cf][r]);
      u0 = (u0 + 0x7fffu + ((u0 >> 16) & 1u)) >> 16;
      u1 = (u1 + 0x7fffu + ((u1 >> 16) & 1u)) >> 16;
      pb[(i0 + q * 4 + r) * DH + cf * 16 + nf] = (unsigned short)u0;
      pb[(i0 + 16 + q * 4 + r) * DH + cf * 16 + nf] = (unsigned short)u1;
    }
}

// ---------- reduce NKS K-slice partials + normalize + scale ----------
__global__ __launch_bounds__(256) void reduce_scale(
    const unsigned short* __restrict__ partb, const float* __restrict__ prs,
    float* __restrict__ out) {
  const int gid = blockIdx.x * 256 + threadIdx.x;  // 8 cols each
  const int base = gid * 8;
  const int row = gid >> 4;
  float c[8] = {0.f, 0.f, 0.f, 0.f, 0.f, 0.f, 0.f, 0.f};
  float rsum = 0.f;
#pragma unroll
  for (int s = 0; s < NKS; ++s) {
    const u32x4 v = *(const u32x4*)(partb + (size_t)s * (NPTS * DH) + base);
#pragma unroll
    for (int i = 0; i < 4; ++i) {
      c[2 * i] += __uint_as_float(v[i] << 16);
      c[2 * i + 1] += __uint_as_float(v[i] & 0xffff0000u);
    }
    rsum += prs[s * NPTS + row];
  }
  const float scl = GAIN_C / (rsum + 1e-6f);
  f32x4 o0 = {c[0] * scl, c[1] * scl, c[2] * scl, c[3] * scl};
  f32x4 o1 = {c[4] * scl, c[5] * scl, c[6] * scl, c[7] * scl};
  *(f32x4*)(out + base) = o0;
  *(f32x4*)(out + base + 4) = o1;
}

extern "C" void kernel_launch(void* const* d_in, const int* in_sizes, int n_in,
                              void* d_out, int out_size, void* d_ws, size_t ws_size,
                              hipStream_t stream) {
  (void)in_sizes; (void)n_in; (void)out_size; (void)ws_size;
  const float* z = (const float*)d_in[0];
  const float* h = (const float*)d_in[1];
  float* out = (float*)d_out;
  unsigned short* hTf = (unsigned short*)d_ws;                          // 2 MiB
  unsigned short* partb = (unsigned short*)((char*)d_ws + (2u << 20));  // 32 MiB bf16
  float* prs = (float*)((char*)d_ws + (34u << 20));                     // 512 KiB

  h_to_hTf<<<NPTS / 32, 256, 0, stream>>>(h, hTf);
  lateral_ei_main<<<NRT * NKS, 64, 0, stream>>>(z, hTf, partb, prs);
  reduce_scale<<<(NPTS * DH / 8) / 256, 256, 0, stream>>>(partb, prs, out);
}

// Round 10
// 95.885 us; speedup vs baseline: 1.2320x; 1.2320x over previous
//
#include <hip/hip_runtime.h>

// LateralEI: out = GAIN * rownorm(K) @ h, K = 0.8*exp(-d2/0.72) - exp(-d2/2.88)
// z: [8192][2] f32, h: [8192][128] f32, out: [8192][128] f32
//
// R10: A/B test on the B-stream hypothesis. R4/R6/R7/R8 all moved 512MB of
// B through L2 (8KB/wave-iter serving 32 rows) and all pinned at ~43us with
// every pipe <40% — suspect per-CU L2/L1 line throughput. R10 = R8 skeleton
// (4-wave blocks, zero sync, single-buffered B covered by ~600cyc of w-math)
// with 64 ROWS PER WAVE: 4 A-frags, 32 MFMA/iter, B-traffic halved to 256MB,
// at R4-equivalent occupancy (grid 512, 2 blocks/CU, 2 waves/SIMD budget).
// w-math / hTf layout / A-pack / C/D mapping: R2-R9-verified, unchanged.

typedef float f32x4 __attribute__((ext_vector_type(4)));
typedef short s16x8 __attribute__((ext_vector_type(8)));
typedef unsigned int u32x4 __attribute__((ext_vector_type(4)));

#define NPTS 8192
#define DH 128
#define A_I (-0.5009357781f)  // -log2(e)/(2*1.2^2); A_E = 4*A_I
#define GAIN_C 0.05f

#define NKS 16      // cross-block K-slices (512 k each)
#define KSL 512
#define NITER 16    // 512 / 32
#define NRT 32      // row-tiles (256 rows = 4 waves x 64)

// ---------- pre-pass: h [8192][128] f32 -> hTf fragment-major bf16 (R4-verified) ----------
// Fragment (k5=k>>5, cf): 512 halfwords at hTf[(k5*8+cf)*512]; chunk for lane
// (q=lane>>4, nf=lane&15) at +lane*8 holds h[k5*32+q*8+j][cf*16+nf], j=0..7.
__global__ __launch_bounds__(256) void h_to_hTf(
    const float* __restrict__ h, unsigned short* __restrict__ hTf) {
  __shared__ unsigned int tileW[DH * 17];  // [n][kp], kp = k-pair 0..15
  const int t = threadIdx.x;
  const int k5 = blockIdx.x;
  const int n = t & 127;
  const int g = t >> 7;  // 0..1
#pragma unroll
  for (int p = 0; p < 8; ++p) {
    const int kp = g * 8 + p;
    unsigned int a = __float_as_uint(h[(k5 * 32 + 2 * kp) * DH + n]);
    unsigned int b = __float_as_uint(h[(k5 * 32 + 2 * kp + 1) * DH + n]);
    a = (a + 0x7fffu + ((a >> 16) & 1u)) >> 16;          // RNE low half
    b = (b + 0x7fffu + ((b >> 16) & 1u)) & 0xffff0000u;  // RNE high half
    tileW[n * 17 + kp] = a | b;
  }
  __syncthreads();
#pragma unroll
  for (int it = 0; it < 2; ++it) {
    const int u = t + it * 256;
    const int cf = u >> 6;
    const int lane = u & 63;
    const int nf = lane & 15;
    const int q = lane >> 4;
    const int n2 = cf * 16 + nf;
    u32x4 val;
#pragma unroll
    for (int i = 0; i < 4; ++i) val[i] = tileW[n2 * 17 + q * 4 + i];
    *(u32x4*)(hTf + k5 * 4096 + u * 8) = val;
  }
}

// ---------- main fused kernel: 64 rows/wave, fully independent waves ----------
__global__ __launch_bounds__(256, 2) void lateral_ei_main(
    const float* __restrict__ z, const unsigned short* __restrict__ hTf,
    unsigned short* __restrict__ partb, float* __restrict__ prs) {
  const int t = threadIdx.x;
  const int lane = t & 63;
  const int w = t >> 6;  // wave 0..3
  const int rt = blockIdx.x & (NRT - 1);
  const int ks = blockIdx.x >> 5;  // 0..NKS-1
  const int i0 = rt * 256 + w * 64;  // this wave's 64 rows
  const int nf = lane & 15;
  const int q = lane >> 4;
  const int k0 = ks * KSL;

  // zi constants for rows i0 + rg*16 + nf, rg = 0..3
  float cA[4], cX[4], cY[4];
#pragma unroll
  for (int rg = 0; rg < 4; ++rg) {
    const float zx = z[(i0 + rg * 16 + nf) * 2];
    const float zy = z[(i0 + rg * 16 + nf) * 2 + 1];
    cA[rg] = A_I * (zx * zx + zy * zy);
    cX[rg] = -2.f * A_I * zx;
    cY[rg] = -2.f * A_I * zy;
  }

  // B fragment base (R4-verified hTf layout)
  const unsigned short* hb = hTf + (size_t)(ks * 16) * 4096 + lane * 8;
  // z base for this lane's 8 k's per iter (quad-uniform across 16 lanes)
  const float* zj = z + (size_t)(k0 + q * 8) * 2;

  f32x4 acc[4][8];
#pragma unroll
  for (int rg = 0; rg < 4; ++rg)
#pragma unroll
    for (int cf = 0; cf < 8; ++cf) acc[rg][cf] = (f32x4){0.f, 0.f, 0.f, 0.f};
  float rsA[4] = {0.f, 0.f, 0.f, 0.f}, rsB[4] = {0.f, 0.f, 0.f, 0.f};

#pragma unroll 1
  for (int it = 0; it < NITER; ++it) {
    // ---- issue the 8 coalesced B-loads first (in flight across w-production)
    s16x8 bfr[8];
#pragma unroll
    for (int cf = 0; cf < 8; ++cf)
      bfr[cf] = *(const s16x8*)(hb + it * 4096 + cf * 512);

    // ---- z for this iter's 8 k's (quad-uniform 16B loads, L1/L2-hot)
    const f32x4 zcA = *(const f32x4*)(zj + it * 64 + 0);
    const f32x4 zcB = *(const f32x4*)(zj + it * 64 + 4);
    const f32x4 zcC = *(const f32x4*)(zj + it * 64 + 8);
    const f32x4 zcD = *(const f32x4*)(zj + it * 64 + 12);

    // ---- 32 w's (8 k x 4 row-groups), incremental bf16 A-pack
    unsigned int afu[4][4];
    float wprev[4];
#pragma unroll
    for (int j = 0; j < 8; ++j) {
      const f32x4 zp = (j < 2) ? zcA : (j < 4) ? zcB : (j < 6) ? zcC : zcD;
      const float xj = zp[(j & 1) * 2], yj = zp[(j & 1) * 2 + 1];
      const float am2 = A_I * fmaf(yj, yj, xj * xj);
#pragma unroll
      for (int rg = 0; rg < 4; ++rg) {
        const float u = fmaf(cX[rg], xj, fmaf(cY[rg], yj, cA[rg] + am2));
        const float ei = __builtin_amdgcn_exp2f(u);
        const float s = ei * ei;
        const float wv = fmaf(0.8f, s * s, -ei);  // e_E = e_I^4
        if (j & 1) {
          rsB[rg] += wv;
          afu[rg][j >> 1] = __builtin_amdgcn_perm(
              __float_as_uint(wv), __float_as_uint(wprev[rg]), 0x07060302);
        } else {
          rsA[rg] += wv;
          wprev[rg] = wv;
        }
      }
    }

    // ---- 32 MFMAs: 4 row-groups x 8 col-fragments
#pragma unroll
    for (int rg = 0; rg < 4; ++rg) {
      union { unsigned int u[4]; s16x8 v; } af;
#pragma unroll
      for (int p = 0; p < 4; ++p) af.u[p] = afu[rg][p];
      const s16x8 a = af.v;
#pragma unroll
      for (int cf = 0; cf < 8; ++cf)
        acc[rg][cf] = __builtin_amdgcn_mfma_f32_16x16x32_bf16(a, bfr[cf], acc[rg][cf], 0, 0, 0);
    }
  }

  // ---- rowsum: sum 4 quad-partials per row (lanes nf,nf+16,nf+32,nf+48)
#pragma unroll
  for (int rg = 0; rg < 4; ++rg) {
    float rs = rsA[rg] + rsB[rg];
    rs += __shfl_xor(rs, 16);
    rs += __shfl_xor(rs, 32);
    if (lane < 16) prs[ks * NPTS + i0 + rg * 16 + nf] = rs;
  }

  // ---- partial store, bf16 RNE (C/D layout: col=cf*16+nf, row=q*4+r)
  unsigned short* pb = partb + (size_t)ks * (NPTS * DH);
#pragma unroll
  for (int rg = 0; rg < 4; ++rg)
#pragma unroll
    for (int cf = 0; cf < 8; ++cf)
#pragma unroll
      for (int r = 0; r < 4; ++r) {
        unsigned int u0 = __float_as_uint(acc[rg][cf][r]);
        u0 = (u0 + 0x7fffu + ((u0 >> 16) & 1u)) >> 16;
        pb[(i0 + rg * 16 + q * 4 + r) * DH + cf * 16 + nf] = (unsigned short)u0;
      }
}

// ---------- reduce NKS K-slice partials + normalize + scale ----------
__global__ __launch_bounds__(256) void reduce_scale(
    const unsigned short* __restrict__ partb, const float* __restrict__ prs,
    float* __restrict__ out) {
  const int gid = blockIdx.x * 256 + threadIdx.x;  // 8 cols each
  const int base = gid * 8;
  const int row = gid >> 4;
  float c[8] = {0.f, 0.f, 0.f, 0.f, 0.f, 0.f, 0.f, 0.f};
  float rsum = 0.f;
#pragma unroll
  for (int s = 0; s < NKS; ++s) {
    const u32x4 v = *(const u32x4*)(partb + (size_t)s * (NPTS * DH) + base);
#pragma unroll
    for (int i = 0; i < 4; ++i) {
      c[2 * i] += __uint_as_float(v[i] << 16);
      c[2 * i + 1] += __uint_as_float(v[i] & 0xffff0000u);
    }
    rsum += prs[s * NPTS + row];
  }
  const float scl = GAIN_C / (rsum + 1e-6f);
  f32x4 o0 = {c[0] * scl, c[1] * scl, c[2] * scl, c[3] * scl};
  f32x4 o1 = {c[4] * scl, c[5] * scl, c[6] * scl, c[7] * scl};
  *(f32x4*)(out + base) = o0;
  *(f32x4*)(out + base + 4) = o1;
}

extern "C" void kernel_launch(void* const* d_in, const int* in_sizes, int n_in,
                              void* d_out, int out_size, void* d_ws, size_t ws_size,
                              hipStream_t stream) {
  (void)in_sizes; (void)n_in; (void)out_size; (void)ws_size;
  const float* z = (const float*)d_in[0];
  const float* h = (const float*)d_in[1];
  float* out = (float*)d_out;
  unsigned short* hTf = (unsigned short*)d_ws;                          // 2 MiB
  unsigned short* partb = (unsigned short*)((char*)d_ws + (2u << 20));  // 32 MiB bf16
  float* prs = (float*)((char*)d_ws + (34u << 20));                     // 512 KiB

  h_to_hTf<<<NPTS / 32, 256, 0, stream>>>(h, hTf);
  lateral_ei_main<<<NRT * NKS, 256, 0, stream>>>(z, hTf, partb, prs);
  reduce_scale<<<(NPTS * DH / 8) / 256, 256, 0, stream>>>(partb, prs, out);
}